// Round 10
// baseline (701.074 us; speedup 1.0000x reference)
//
#include <hip/hip_runtime.h>
#include <stdint.h>

typedef short short8 __attribute__((ext_vector_type(8)));
typedef float f32x4 __attribute__((ext_vector_type(4)));

#define D 128
#define LOG2E 1.44269504088896340736f
#define NGG  2              // graphs per group (sequential)
#define NGRP 3              // 4-wave groups per block
#define GPBLK (NGG * NGRP)  // graphs per block

__device__ __forceinline__ unsigned short f2bf(float f) {
    union { float f; unsigned u; } v; v.f = f;
    unsigned u = v.u;
    unsigned r = (u + 0x7FFFu + ((u >> 16) & 1u)) >> 16;  // RNE
    return (unsigned short)r;
}

// pack two f32 -> one u32 of two bf16 (round-half-up via +0x8000, then v_perm)
__device__ __forceinline__ unsigned packbf(float x, float y) {
    unsigned ux = __float_as_uint(x) + 0x8000u;
    unsigned uy = __float_as_uint(y) + 0x8000u;
    return __builtin_amdgcn_perm(uy, ux, 0x07060302u);
}

// DPP butterfly add within 16-lane groups (verified rounds 5-9).
template <int C>
__device__ __forceinline__ float dpp_add(float x) {
    int y = __builtin_amdgcn_update_dpp(0, __float_as_int(x), C, 0xF, 0xF, true);
    return x + __int_as_float(y);
}
__device__ __forceinline__ float red16(float x) {
    x = dpp_add<0xB1>(x);
    x = dpp_add<0x4E>(x);
    x = dpp_add<0x141>(x);
    x = dpp_add<0x140>(x);
    return x;
}

// HBM -> LDS direct (16B per lane). LDS dest must be linear base + lane*16.
__device__ __forceinline__ void gld16(const float* g, float* l) {
    __builtin_amdgcn_global_load_lds(
        (const __attribute__((address_space(1))) void*)g,
        (__attribute__((address_space(3))) void*)l, 16, 0, 0);
}

// ---------------------------------------------------------------------------
// Kernel 1: pre-pack (Wu * log2e) as bf16 MFMA B-fragments.
// t = nt*256 + kk*64 + lane holds B[k][col], col = nt*16+(lane&15),
// k = kk*32+(lane>>4)*8+j  (B[k][col] = Wu[col][k], u = f @ Wu^T)
// ---------------------------------------------------------------------------
__global__ __launch_bounds__(256) void pack_wu(const float* __restrict__ Wu,
                                               short8* __restrict__ frag) {
    int tid = blockIdx.x * 256 + threadIdx.x;
    int nt = tid >> 8, kk = (tid >> 6) & 3, l = tid & 63;
    int col = nt * 16 + (l & 15);
    int kb  = kk * 32 + ((l >> 4) * 8);
    short8 o;
#pragma unroll
    for (int j = 0; j < 8; ++j) o[j] = (short)f2bf(Wu[col * D + kb + j] * LOG2E);
    frag[tid] = o;
}

// ---------------------------------------------------------------------------
// Kernel 2: per-graph gate factors  c = 2^{-(Wv·x_last + bu)·log2e}.
// 16 graphs per block; Wv stays L1/L2-hot. (Validated round 5.)
// ---------------------------------------------------------------------------
__global__ __launch_bounds__(256) void gate_k(const float* __restrict__ xI,
                                              const float* __restrict__ xV,
                                              const float* __restrict__ Wv,
                                              const float* __restrict__ bu,
                                              const int* __restrict__ lastn,
                                              float* __restrict__ cIb,
                                              float* __restrict__ cVb, int B) {
    __shared__ __align__(16) float xs[4][2][D];
    int t = threadIdx.x, h = t & 127, st = t >> 7;
    float bias = bu[h];
    const float4* wv4 = (const float4*)(Wv + (size_t)h * D);
    const float* src = st ? xV : xI;
    float* dst = st ? cVb : cIb;
    int g0 = blockIdx.x * 16;
    for (int p = 0; p < 4; ++p) {
        int gb = g0 + p * 4;
#pragma unroll
        for (int j = 0; j < 4; ++j) {
            int gg = gb + j; if (gg >= B) gg = B - 1;
            xs[j][st][h] = src[(size_t)lastn[gg] * D + h];
        }
        __syncthreads();
        const float4* x0 = (const float4*)xs[0][st];
        const float4* x1 = (const float4*)xs[1][st];
        const float4* x2 = (const float4*)xs[2][st];
        const float4* x3 = (const float4*)xs[3][st];
        float a0 = 0.f, a1 = 0.f, a2 = 0.f, a3 = 0.f;
#pragma unroll
        for (int i = 0; i < 32; ++i) {
            float4 w = wv4[i], b;
            b = x0[i]; a0 += w.x*b.x + w.y*b.y + w.z*b.z + w.w*b.w;
            b = x1[i]; a1 += w.x*b.x + w.y*b.y + w.z*b.z + w.w*b.w;
            b = x2[i]; a2 += w.x*b.x + w.y*b.y + w.z*b.z + w.w*b.w;
            b = x3[i]; a3 += w.x*b.x + w.y*b.y + w.z*b.z + w.w*b.w;
        }
        if (gb + 0 < B) dst[(size_t)(gb+0)*D + h] = __builtin_amdgcn_exp2f(-(a0+bias)*LOG2E);
        if (gb + 1 < B) dst[(size_t)(gb+1)*D + h] = __builtin_amdgcn_exp2f(-(a1+bias)*LOG2E);
        if (gb + 2 < B) dst[(size_t)(gb+2)*D + h] = __builtin_amdgcn_exp2f(-(a2+bias)*LOG2E);
        if (gb + 3 < B) dst[(size_t)(gb+3)*D + h] = __builtin_amdgcn_exp2f(-(a3+bias)*LOG2E);
        __syncthreads();
    }
}

// ---------------------------------------------------------------------------
// Kernel 3: fused main, MEGA-BLOCK. 768 threads = 12 waves = 3 groups x 4
// waves; ONE shared bfrag (32 KB) + per-wave 8 KB gld staging (96 KB) -> one
// block per CU, 12 r4-style pipelined waves. Each group processes NGG
// consecutive graphs; waves stride 16-row chunks. Per chunk:
//   vmcnt(0) [stage c landed] -> af+fr regs from LDS -> lgkmcnt(0) ->
//   issue gld for c+4 (hides under the rest) -> MFMA+epilogue -> red16 ->
//   weights 2^e (no online max, r9-validated) -> accumulate.
// ---------------------------------------------------------------------------
__global__ __launch_bounds__(768) void attn_main(
    const float* __restrict__ xI, const float* __restrict__ xV,
    const float* __restrict__ We, const int* __restrict__ lastn,
    const float* __restrict__ cIb, const float* __restrict__ cVb,
    const short8* __restrict__ fragG, float* __restrict__ out, int B) {
    __shared__ short8 bfrag[2048];                    // 32 KB Wu fragments
    __shared__ __align__(16) float stage[12][2048];   // 96 KB row staging
    __shared__ __align__(16) float wt[12][16][2];     // per-wave weights
    __shared__ float cmbA[NGRP][2][4][D];             // per-group combine
    __shared__ float cmbL[NGRP][2][4];

    int t = threadIdx.x, lane = t & 63, w = t >> 6;
    int grp = w >> 2, wiw = w & 3;

    {   // stage Wu fragments once per block (768 threads over 2048 uint4)
        const uint4* srcf = (const uint4*)fragG;
        uint4* dst = (uint4*)bfrag;
#pragma unroll
        for (int i = 0; i < 3; ++i) {
            int idx = i * 768 + t;
            if (idx < 2048) dst[idx] = srcf[idx];
        }
    }
    float WeR[8];                                     // graph-independent
#pragma unroll
    for (int nt = 0; nt < 8; ++nt) WeR[nt] = We[nt * 16 + (lane & 15)] * LOG2E;
    __syncthreads();

    float* rb = &stage[w][0];
    const char* rbc = (const char*)rb;

    // per-lane address constants (graph-independent)
    int loff[8];                    // global float-offset per staging load
#pragma unroll
    for (int i = 0; i < 8; ++i) {
        int row = (i << 1) + (lane >> 5);
        loff[i] = (row << 7) + (((lane & 31) ^ (row & 7)) << 2);
    }
    int arow = lane & 15;
    int sw = (arow & 7) << 4;
    int ab0 = ((arow << 9) + ((lane >> 4) << 5)) ^ sw;
    int ab1 = ((arow << 9) + ((lane >> 4) << 5) + 16) ^ sw;

    int g0 = blockIdx.x * GPBLK + grp * NGG;

    for (int gi = 0; gi < NGG; ++gi) {
        int g = g0 + gi;
        bool act = (g < B);
        int s = 0, n = 0, ch = 0, total = 0;
        float cIr[8], cVr[8];
        if (act) {
            s = (g == 0) ? 0 : (lastn[g - 1] + 1);
            n = lastn[g] + 1 - s;                     // >= 1
#pragma unroll
            for (int nt = 0; nt < 8; ++nt) {
                int col = nt * 16 + (lane & 15);
                cIr[nt] = cIb[(size_t)g * D + col];
                cVr[nt] = cVb[(size_t)g * D + col];
            }
            ch = (n + 15) >> 4;
            total = 2 * ch;
        }

        float lIs = 0.f, lVs = 0.f;
        float aI0 = 0.f, aI1 = 0.f, aV0 = 0.f, aV1 = 0.f;

        // issue 8 global_load_lds for chunk cc into this wave's stage buffer
        auto issue = [&](int cc) {
            int hf = (cc >= ch) ? 1 : 0;
            const float* sp = (hf ? xV : xI) + ((size_t)s << 7);
            int bb = (cc - hf * ch) << 4;
            if (bb + 16 <= n) {        // interior: no clamps
                const float* pb = sp + ((size_t)bb << 7);
#pragma unroll
                for (int i = 0; i < 8; ++i)
                    gld16(pb + loff[i], rb + (i << 8) + (lane << 2));
            } else {                   // tail: clamp rows (masked later)
#pragma unroll
                for (int i = 0; i < 8; ++i) {
                    int row = (i << 1) + (lane >> 5);
                    int rr = bb + row; if (rr > n - 1) rr = n - 1;
                    int lu = (lane & 31) ^ (row & 7);
                    gld16(sp + ((size_t)rr << 7) + (lu << 2),
                          rb + (i << 8) + (lane << 2));
                }
            }
        };

        if (wiw < total) issue(wiw);

        for (int c = wiw; c < total; c += 4) {
            int hf = (c >= ch) ? 1 : 0;
            int base = (c - hf * ch) << 4;

            asm volatile("s_waitcnt vmcnt(0)" ::: "memory");  // stage landed
            __builtin_amdgcn_sched_barrier(0);

            // ---- A fragments from stage ----
            short8 af[4];
#pragma unroll
            for (int kk = 0; kk < 4; ++kk) {
                float4 f0 = *(const float4*)(rbc + ab0 + (kk << 7));
                float4 f1 = *(const float4*)(rbc + ab1 + (kk << 7));
                union { unsigned u[4]; short8 s8; } cv;
                cv.u[0] = packbf(f0.x, f0.y);
                cv.u[1] = packbf(f0.z, f0.w);
                cv.u[2] = packbf(f1.x, f1.y);
                cv.u[3] = packbf(f1.z, f1.w);
                af[kk] = cv.s8;
            }
            // ---- accumulate operands (dims 2*lane, 2*lane+1) from stage --
            float2 fr[16];
#pragma unroll
            for (int r = 0; r < 16; ++r)
                fr[r] = *(const float2*)(rbc + ((((r << 9) + (lane << 3)))
                                               ^ ((r & 7) << 4)));
            asm volatile("s_waitcnt lgkmcnt(0)" ::: "memory"); // stage free
            __builtin_amdgcn_sched_barrier(0);
            if (c + 4 < total) issue(c + 4);   // hides under all work below

            // ---- GEMM + gate epilogue (shared exp2 + shared rcp) ----
            float pI[4] = {0.f, 0.f, 0.f, 0.f}, pV[4] = {0.f, 0.f, 0.f, 0.f};
#pragma unroll
            for (int nt = 0; nt < 8; ++nt) {
                f32x4 dacc = {0.f, 0.f, 0.f, 0.f};
#pragma unroll
                for (int kk = 0; kk < 4; ++kk)
                    dacc = __builtin_amdgcn_mfma_f32_16x16x32_bf16(
                        af[kk], bfrag[nt * 256 + kk * 64 + lane], dacc, 0, 0, 0);
#pragma unroll
                for (int q = 0; q < 4; ++q) {
                    float t2 = __builtin_amdgcn_exp2f(-dacc[q]);
                    float dI = fmaf(t2, cIr[nt], 1.f);
                    float dV = fmaf(t2, cVr[nt], 1.f);
                    float rr = __builtin_amdgcn_rcpf(dI * dV);
                    pI[q] = fmaf(WeR[nt], dV * rr, pI[q]);   // WeR/dI
                    pV[q] = fmaf(WeR[nt], dI * rr, pV[q]);   // WeR/dV
                }
            }
            // ---- reduce e across 16 lanes; weights = 2^e (bounded) ----
#pragma unroll
            for (int q = 0; q < 4; ++q) { pI[q] = red16(pI[q]); pV[q] = red16(pV[q]); }
            if (base + 16 > n) {
#pragma unroll
                for (int q = 0; q < 4; ++q) {
                    int r = ((lane >> 4) << 2) + q;
                    if (base + r >= n) { pI[q] = -__builtin_inff(); pV[q] = -__builtin_inff(); }
                }
            }
            float wIq[4], wVq[4];
#pragma unroll
            for (int q = 0; q < 4; ++q) {
                wIq[q] = __builtin_amdgcn_exp2f(pI[q]);   // 0 for masked rows
                wVq[q] = __builtin_amdgcn_exp2f(pV[q]);
            }
            lIs += (wIq[0] + wIq[1]) + (wIq[2] + wIq[3]);  // quarter-local
            lVs += (wVq[0] + wVq[1]) + (wVq[2] + wVq[3]);

            // publish weights to per-wave LDS table (same-wave DS ordering)
            if ((lane & 15) == 0) {
                int gq = lane >> 4;
                float4 w0 = {wIq[0], wVq[0], wIq[1], wVq[1]};
                float4 w1 = {wIq[2], wVq[2], wIq[3], wVq[3]};
                *(float4*)&wt[w][gq * 4 + 0][0] = w0;
                *(float4*)&wt[w][gq * 4 + 2][0] = w1;
            }

            // ---- weighted accumulate (pure fma chains) ----
#pragma unroll
            for (int r = 0; r < 16; ++r) {
                float2 f = fr[r];
                float2 wv = *(const float2*)&wt[w][r][0];
                aI0 = fmaf(wv.x, f.x, aI0); aI1 = fmaf(wv.x, f.y, aI1);
                aV0 = fmaf(wv.y, f.x, aV0); aV1 = fmaf(wv.y, f.y, aV1);
            }
        }

        // finalize lane-local l: sum the 4 quarters (once per graph)
        lIs += __shfl_xor(lIs, 16); lIs += __shfl_xor(lIs, 32);
        lVs += __shfl_xor(lVs, 16); lVs += __shfl_xor(lVs, 32);

        // ---- per-group combine (block-wide barriers, unconditional) ----
        __syncthreads();   // WAR vs previous graph's combine reads
        if (act) {
            float2 vI = {aI0, aI1}, vV = {aV0, aV1};
            *(float2*)&cmbA[grp][0][wiw][lane * 2] = vI;
            *(float2*)&cmbA[grp][1][wiw][lane * 2] = vV;
            if (lane == 0) { cmbL[grp][0][wiw] = lIs; cmbL[grp][1][wiw] = lVs; }
        }
        __syncthreads();
        if (act) {
            int tig = wiw * 64 + lane;         // 0..255 within group
            int st = tig >> 7, d = tig & 127;
            float Ls = (cmbL[grp][st][0] + cmbL[grp][st][1]) +
                       (cmbL[grp][st][2] + cmbL[grp][st][3]);
            float A  = (cmbA[grp][st][0][d] + cmbA[grp][st][1][d]) +
                       (cmbA[grp][st][2][d] + cmbA[grp][st][3][d]);
            out[(size_t)st * B * D + (size_t)g * D + d] = A * __builtin_amdgcn_rcpf(Ls);
        }
    }
}

// ---------------------------------------------------------------------------
extern "C" void kernel_launch(void* const* d_in, const int* in_sizes, int n_in,
                              void* d_out, int out_size, void* d_ws, size_t ws_size,
                              hipStream_t stream) {
    const float* xI    = (const float*)d_in[0];
    const float* xV    = (const float*)d_in[1];
    const float* Wu    = (const float*)d_in[2];
    const float* bu    = (const float*)d_in[3];
    const float* Wv    = (const float*)d_in[4];
    const float* We    = (const float*)d_in[5];
    // d_in[6] = seg_ids (unused: segments contiguous, last_nodes suffices)
    const int*   lastn = (const int*)d_in[7];
    const int B = in_sizes[7];               // 8192

    float*  cIb   = (float*)d_ws;
    float*  cVb   = cIb + (size_t)B * D;
    short8* fragW = (short8*)(cVb + (size_t)B * D);

    pack_wu<<<8, 256, 0, stream>>>(Wu, fragW);
    gate_k<<<(B + 15) / 16, 256, 0, stream>>>(xI, xV, Wv, bu, lastn, cIb, cVb, B);
    int nblk = (B + GPBLK - 1) / GPBLK;
    attn_main<<<nblk, 768, 0, stream>>>(xI, xV, We, lastn, cIb, cVb, fragW,
                                        (float*)d_out, B);
}

// Round 11
// 301.416 us; speedup vs baseline: 2.3259x; 2.3259x over previous
//
#include <hip/hip_runtime.h>
#include <stdint.h>

typedef short short8 __attribute__((ext_vector_type(8)));
typedef float f32x4 __attribute__((ext_vector_type(4)));

#define D 128
#define LOG2E 1.44269504088896340736f

__device__ __forceinline__ unsigned short f2bf(float f) {
    union { float f; unsigned u; } v; v.f = f;
    unsigned u = v.u;
    unsigned r = (u + 0x7FFFu + ((u >> 16) & 1u)) >> 16;  // RNE
    return (unsigned short)r;
}

// pack two f32 -> one u32 of two bf16 (round-half-up via +0x8000, then v_perm)
__device__ __forceinline__ unsigned packbf(float x, float y) {
    unsigned ux = __float_as_uint(x) + 0x8000u;
    unsigned uy = __float_as_uint(y) + 0x8000u;
    return __builtin_amdgcn_perm(uy, ux, 0x07060302u);
}

// DPP butterfly add within 16-lane groups (verified rounds 5-10).
template <int C>
__device__ __forceinline__ float dpp_add(float x) {
    int y = __builtin_amdgcn_update_dpp(0, __float_as_int(x), C, 0xF, 0xF, true);
    return x + __int_as_float(y);
}
__device__ __forceinline__ float red16(float x) {
    x = dpp_add<0xB1>(x);
    x = dpp_add<0x4E>(x);
    x = dpp_add<0x141>(x);
    x = dpp_add<0x140>(x);
    return x;
}

// ---------------------------------------------------------------------------
// Kernel 1: pre-pack (Wu * log2e) as bf16 MFMA B-fragments. (verified)
// ---------------------------------------------------------------------------
__global__ __launch_bounds__(256) void pack_wu(const float* __restrict__ Wu,
                                               short8* __restrict__ frag) {
    int tid = blockIdx.x * 256 + threadIdx.x;
    int nt = tid >> 8, kk = (tid >> 6) & 3, l = tid & 63;
    int col = nt * 16 + (l & 15);
    int kb  = kk * 32 + ((l >> 4) * 8);
    short8 o;
#pragma unroll
    for (int j = 0; j < 8; ++j) o[j] = (short)f2bf(Wu[col * D + kb + j] * LOG2E);
    frag[tid] = o;
}

// ---------------------------------------------------------------------------
// Kernel 2: per-graph gate factors  c = 2^{-(Wv·x_last + bu)·log2e}. (verified)
// ---------------------------------------------------------------------------
__global__ __launch_bounds__(256) void gate_k(const float* __restrict__ xI,
                                              const float* __restrict__ xV,
                                              const float* __restrict__ Wv,
                                              const float* __restrict__ bu,
                                              const int* __restrict__ lastn,
                                              float* __restrict__ cIb,
                                              float* __restrict__ cVb, int B) {
    __shared__ __align__(16) float xs[4][2][D];
    int t = threadIdx.x, h = t & 127, st = t >> 7;
    float bias = bu[h];
    const float4* wv4 = (const float4*)(Wv + (size_t)h * D);
    const float* src = st ? xV : xI;
    float* dst = st ? cVb : cIb;
    int g0 = blockIdx.x * 16;
    for (int p = 0; p < 4; ++p) {
        int gb = g0 + p * 4;
#pragma unroll
        for (int j = 0; j < 4; ++j) {
            int gg = gb + j; if (gg >= B) gg = B - 1;
            xs[j][st][h] = src[(size_t)lastn[gg] * D + h];
        }
        __syncthreads();
        const float4* x0 = (const float4*)xs[0][st];
        const float4* x1 = (const float4*)xs[1][st];
        const float4* x2 = (const float4*)xs[2][st];
        const float4* x3 = (const float4*)xs[3][st];
        float a0 = 0.f, a1 = 0.f, a2 = 0.f, a3 = 0.f;
#pragma unroll
        for (int i = 0; i < 32; ++i) {
            float4 w = wv4[i], b;
            b = x0[i]; a0 += w.x*b.x + w.y*b.y + w.z*b.z + w.w*b.w;
            b = x1[i]; a1 += w.x*b.x + w.y*b.y + w.z*b.z + w.w*b.w;
            b = x2[i]; a2 += w.x*b.x + w.y*b.y + w.z*b.z + w.w*b.w;
            b = x3[i]; a3 += w.x*b.x + w.y*b.y + w.z*b.z + w.w*b.w;
        }
        if (gb + 0 < B) dst[(size_t)(gb+0)*D + h] = __builtin_amdgcn_exp2f(-(a0+bias)*LOG2E);
        if (gb + 1 < B) dst[(size_t)(gb+1)*D + h] = __builtin_amdgcn_exp2f(-(a1+bias)*LOG2E);
        if (gb + 2 < B) dst[(size_t)(gb+2)*D + h] = __builtin_amdgcn_exp2f(-(a2+bias)*LOG2E);
        if (gb + 3 < B) dst[(size_t)(gb+3)*D + h] = __builtin_amdgcn_exp2f(-(a3+bias)*LOG2E);
        __syncthreads();
    }
}

// ---------------------------------------------------------------------------
// Kernel 3: ROW-TILE pass. Block = 256 contiguous rows of one half (xI or
// xV); wave = 64 contiguous rows = 4 rowgroups of 16. No graph-granular
// blocks: per quarter-row graph ids come from seg_ids, gate factors fetched
// from L1/L2-hot cIb/cVb. Weights w = 2^e need NO max (r9-validated bound),
// so per-graph outputs are plain global sums: waves keep running per-segment
// partials and flush with atomicAdd only at segment boundaries (~2/wave).
// Accumulates directly into d_out (pre-zeroed); l-sums into lAcc.
// ---------------------------------------------------------------------------
__global__ __launch_bounds__(256) void tile_k(
    const float* __restrict__ xI, const float* __restrict__ xV,
    const float* __restrict__ We, const int* __restrict__ seg,
    const float* __restrict__ cIb, const float* __restrict__ cVb,
    const short8* __restrict__ fragG,
    float* __restrict__ acc,      // = d_out: [2][B][D], pre-zeroed
    float* __restrict__ lAcc,     // [2][B], pre-zeroed
    int N, int B, int nBS) {
    __shared__ short8 bfrag[2048];                // 32 KB Wu fragments
    __shared__ __align__(16) float wt[4][16][2];  // per-wave weight table

    int t = threadIdx.x, lane = t & 63, w = t >> 6;
    {   // stage Wu fragments once per block (contiguous 16B/lane)
        const uint4* srcf = (const uint4*)fragG;
        uint4* dst = (uint4*)bfrag;
#pragma unroll
        for (int i = 0; i < 8; ++i) dst[i * 256 + t] = srcf[i * 256 + t];
    }
    float WeR[8];
#pragma unroll
    for (int nt = 0; nt < 8; ++nt) WeR[nt] = We[nt * 16 + (lane & 15)] * LOG2E;
    __syncthreads();

    int bid = blockIdx.x;
    int strm = (bid >= nBS) ? 1 : 0;
    const float* xs = strm ? xV : xI;
    float* accI = acc;
    float* accV = acc + (size_t)B * D;
    int rowBase = (bid - strm * nBS) * 256 + w * 64;

    // running per-segment partials (carried across rowgroups)
    int curG = -1;
    float sI0=0.f, sI1=0.f, sV0=0.f, sV1=0.f, lsI=0.f, lsV=0.f;

    for (int rg = 0; rg < 4; ++rg) {
        int rbase = rowBase + rg * 16;
        if (rbase >= N) break;

        // ---- A fragments direct from global (line-coalesced, read-once) --
        int arow = rbase + (lane & 15); if (arow > N - 1) arow = N - 1;
        const float* rp = xs + (size_t)arow * D + ((lane >> 4) << 3);
        short8 af[4];
#pragma unroll
        for (int kk = 0; kk < 4; ++kk) {
            float4 f0 = *(const float4*)(rp + kk * 32);
            float4 f1 = *(const float4*)(rp + kk * 32 + 4);
            union { unsigned u[4]; short8 s8; } cv;
            cv.u[0] = packbf(f0.x, f0.y);
            cv.u[1] = packbf(f0.z, f0.w);
            cv.u[2] = packbf(f1.x, f1.y);
            cv.u[3] = packbf(f1.z, f1.w);
            af[kk] = cv.s8;
        }

        // graph base offsets for this lane's 4 accumulator rows
        int g4D[4];
#pragma unroll
        for (int q = 0; q < 4; ++q) {
            int r = rbase + ((lane >> 4) << 2) + q; if (r > N - 1) r = N - 1;
            g4D[q] = seg[r] << 7;
        }

        // ---- GEMM + gate epilogue (gates per quarter-row graph) ----
        float pI[4] = {0.f,0.f,0.f,0.f}, pV[4] = {0.f,0.f,0.f,0.f};
#pragma unroll
        for (int nt = 0; nt < 8; ++nt) {
            int col = nt * 16 + (lane & 15);
            float cI4[4], cV4[4];
#pragma unroll
            for (int q = 0; q < 4; ++q) {
                cI4[q] = cIb[g4D[q] + col];
                cV4[q] = cVb[g4D[q] + col];
            }
            f32x4 dacc = {0.f, 0.f, 0.f, 0.f};
#pragma unroll
            for (int kk = 0; kk < 4; ++kk)
                dacc = __builtin_amdgcn_mfma_f32_16x16x32_bf16(
                    af[kk], bfrag[nt * 256 + kk * 64 + lane], dacc, 0, 0, 0);
#pragma unroll
            for (int q = 0; q < 4; ++q) {
                float t2 = __builtin_amdgcn_exp2f(-dacc[q]);
                float dI = fmaf(t2, cI4[q], 1.f);
                float dV = fmaf(t2, cV4[q], 1.f);
                float rr = __builtin_amdgcn_rcpf(dI * dV);
                pI[q] = fmaf(WeR[nt], dV * rr, pI[q]);   // WeR/dI
                pV[q] = fmaf(WeR[nt], dI * rr, pV[q]);   // WeR/dV
            }
        }
#pragma unroll
        for (int q = 0; q < 4; ++q) { pI[q] = red16(pI[q]); pV[q] = red16(pV[q]); }
        if (rbase + 16 > N) {
#pragma unroll
            for (int q = 0; q < 4; ++q) {
                int r = rbase + ((lane >> 4) << 2) + q;
                if (r >= N) { pI[q] = -__builtin_inff(); pV[q] = -__builtin_inff(); }
            }
        }
        float wIq[4], wVq[4];
#pragma unroll
        for (int q = 0; q < 4; ++q) {
            wIq[q] = __builtin_amdgcn_exp2f(pI[q]);   // bounded; 0 if masked
            wVq[q] = __builtin_amdgcn_exp2f(pV[q]);
        }
        if ((lane & 15) == 0) {
            int gq = lane >> 4;
            float4 w0 = {wIq[0], wVq[0], wIq[1], wVq[1]};
            float4 w1 = {wIq[2], wVq[2], wIq[3], wVq[3]};
            *(float4*)&wt[w][gq * 4 + 0][0] = w0;
            *(float4*)&wt[w][gq * 4 + 2][0] = w1;
        }

        // ---- weighted accumulate with boundary flush ----
        const float2* s2 = (const float2*)xs;
        for (int r = 0; r < 16; ++r) {
            int rr = rbase + r; int rc = rr > N - 1 ? N - 1 : rr;
            int gr = seg[rc];                       // wave-uniform
            if (gr != curG) {                       // uniform branch, rare
                if (curG >= 0) {
                    size_t o = ((size_t)curG << 7) + (lane << 1);
                    atomicAdd(&accI[o], sI0);     atomicAdd(&accI[o + 1], sI1);
                    atomicAdd(&accV[o], sV0);     atomicAdd(&accV[o + 1], sV1);
                    if (lane == 0) {
                        atomicAdd(&lAcc[curG], lsI);
                        atomicAdd(&lAcc[B + curG], lsV);
                    }
                }
                curG = gr; sI0 = sI1 = sV0 = sV1 = lsI = lsV = 0.f;
            }
            float2 f = s2[((size_t)rc << 6) + lane];   // L1-hot (af touched)
            float2 wv = *(const float2*)&wt[w][r][0];  // {wI, wV}, uniform
            sI0 = fmaf(wv.x, f.x, sI0); sI1 = fmaf(wv.x, f.y, sI1);
            sV0 = fmaf(wv.y, f.x, sV0); sV1 = fmaf(wv.y, f.y, sV1);
            lsI += wv.x; lsV += wv.y;
        }
    }
    if (curG >= 0) {                                // final flush
        size_t o = ((size_t)curG << 7) + (lane << 1);
        atomicAdd(&accI[o], sI0);     atomicAdd(&accI[o + 1], sI1);
        atomicAdd(&accV[o], sV0);     atomicAdd(&accV[o + 1], sV1);
        if (lane == 0) {
            atomicAdd(&lAcc[curG], lsI);
            atomicAdd(&lAcc[B + curG], lsV);
        }
    }
}

// ---------------------------------------------------------------------------
// Kernel 4: normalize in place: out = acc / l.
// ---------------------------------------------------------------------------
__global__ __launch_bounds__(256) void final_k(float* __restrict__ outp,
                                               const float* __restrict__ lAcc,
                                               int B) {
    int idx = blockIdx.x * 256 + threadIdx.x;     // < 2*B*D
    int bd = B * D;
    int st = (idx >= bd) ? 1 : 0;
    int g = (idx - st * bd) >> 7;
    outp[idx] = outp[idx] * __builtin_amdgcn_rcpf(lAcc[st * B + g]);
}

// ---------------------------------------------------------------------------
extern "C" void kernel_launch(void* const* d_in, const int* in_sizes, int n_in,
                              void* d_out, int out_size, void* d_ws, size_t ws_size,
                              hipStream_t stream) {
    const float* xI    = (const float*)d_in[0];
    const float* xV    = (const float*)d_in[1];
    const float* Wu    = (const float*)d_in[2];
    const float* bu    = (const float*)d_in[3];
    const float* Wv    = (const float*)d_in[4];
    const float* We    = (const float*)d_in[5];
    const int*   seg   = (const int*)d_in[6];
    const int*   lastn = (const int*)d_in[7];
    const int B = in_sizes[7];               // 8192
    const int N = in_sizes[0] / D;           // 500000

    float*  cIb   = (float*)d_ws;
    float*  cVb   = cIb + (size_t)B * D;
    short8* fragW = (short8*)(cVb + (size_t)B * D);
    float*  lAcc  = (float*)(fragW + 2048);  // [2][B]

    hipMemsetAsync(d_out, 0, (size_t)2 * B * D * sizeof(float), stream);
    hipMemsetAsync(lAcc, 0, (size_t)2 * B * sizeof(float), stream);

    pack_wu<<<8, 256, 0, stream>>>(Wu, fragW);
    gate_k<<<(B + 15) / 16, 256, 0, stream>>>(xI, xV, Wv, bu, lastn, cIb, cVb, B);
    int nBS = (N + 255) / 256;
    tile_k<<<2 * nBS, 256, 0, stream>>>(xI, xV, We, seg, cIb, cVb, fragW,
                                        (float*)d_out, lAcc, N, B, nBS);
    final_k<<<(2 * B * D) / 256, 256, 0, stream>>>((float*)d_out, lAcc, B);
}